// Round 12
// baseline (6382.097 us; speedup 1.0000x reference)
//
#include <hip/hip_runtime.h>

#define TT 4096
#define BB 64
#define RR 16
#define OUT_HID (BB*TT)
#define SPINMAX 100000   // bounded spin -> wrong answer instead of GPU hang

#define SYS_LDU(p)    __hip_atomic_load((p),      __ATOMIC_RELAXED, __HIP_MEMORY_SCOPE_SYSTEM)
#define SYS_STU(p,v)  __hip_atomic_store((p),(v), __ATOMIC_RELAXED, __HIP_MEMORY_SCOPE_SYSTEM)
#define SYS_STF(p,v)  __hip_atomic_store((p),(v), __ATOMIC_RELAXED, __HIP_MEMORY_SCOPE_SYSTEM)

__device__ __forceinline__ float sigm(float x) {
    return __builtin_amdgcn_rcpf(1.0f + __expf(-x));
}
__device__ __forceinline__ float tanhfast(float x) {
    return 1.0f - 2.0f * __builtin_amdgcn_rcpf(1.0f + __expf(2.0f * x));
}

// Bounded spin until *p == want; sticky `dead` keeps failures terminating.
#define WAIT_EQ(p, want, cur, dead)                                           \
    if (!(dead)) {                                                            \
        int k_ = 0;                                                           \
        while ((cur) != (unsigned)(want)) {                                   \
            if (++k_ > SPINMAX) { (dead) = true; break; }                     \
            __builtin_amdgcn_s_sleep(1); (cur) = SYS_LDU(p);                  \
        }                                                                     \
    }

#define FMA4(acc, wv, hv)                                            \
    acc = fmaf((wv).x, (hv).x, acc); acc = fmaf((wv).y, (hv).y, acc); \
    acc = fmaf((wv).z, (hv).z, acc); acc = fmaf((wv).w, (hv).w, acc);

#define X4(M) M(0) M(1) M(2) M(3)

// Pin one float4 via 4 scalar "+v" ties (blocks remat/sinking of the loads).
#define PIN1(vv) { float _t0 = (vv).x, _t1 = (vv).y, _t2 = (vv).z, _t3 = (vv).w; \
    asm volatile("" : "+v"(_t0), "+v"(_t1), "+v"(_t2), "+v"(_t3));              \
    (vv).x = _t0; (vv).y = _t1; (vv).z = _t2; (vv).w = _t3; }

// 48 weight floats/thread: rows u, u+128, u+256; col chunks 8i+c (i=0..3).
#define DECLW(i) float4 wA##i, wB##i, wC##i;
#define LDW(i)   wA##i = *(const float4*)(rpA + 32*(i)); \
                 wB##i = *(const float4*)(rpB + 32*(i)); \
                 wC##i = *(const float4*)(rpC + 32*(i));
#define PINW(i)  PIN1(wA##i) PIN1(wB##i) PIN1(wC##i)
#define GEMV_LDS(i) { float4 hv_ = hb4[8*(i) + c]; \
    FMA4(a0, wA##i, hv_); FMA4(a1, wB##i, hv_); FMA4(a2, wC##i, hv_); }
#define GEMV_YA(i) { FMA4(a0, wA##i, yA##i); FMA4(a1, wB##i, yA##i); FMA4(a2, wC##i, yA##i); }
#define GEMV_YB(i) { FMA4(a0, wA##i, yB##i); FMA4(a1, wB##i, yB##i); FMA4(a2, wC##i, yB##i); }

// 8-lane-group reduction (lanes c=0..7 of each unit)
#define RED3() \
    float A0 = a0 + __shfl_xor(a0, 1); A0 += __shfl_xor(A0, 2); A0 += __shfl_xor(A0, 4); \
    float A1 = a1 + __shfl_xor(a1, 1); A1 += __shfl_xor(A1, 2); A1 += __shfl_xor(A1, 4); \
    float A2 = a2 + __shfl_xor(a2, 1); A2 += __shfl_xor(A2, 2); A2 += __shfl_xor(A2, 4);

// issue-only y loads (wait happens next iteration, hidden under compute)
#define LOADY(B0,B1,B2,B3,p) asm volatile(                        \
    "global_load_dwordx4 %0, %4, off sc0 sc1\n\t"                 \
    "global_load_dwordx4 %1, %4, off offset:128 sc0 sc1\n\t"      \
    "global_load_dwordx4 %2, %4, off offset:256 sc0 sc1\n\t"      \
    "global_load_dwordx4 %3, %4, off offset:384 sc0 sc1"          \
    : "=&v"(B0), "=&v"(B1), "=&v"(B2), "=&v"(B3) : "v"(p) : "memory");
#define WAITV  { asm volatile("s_waitcnt vmcnt(0)" ::: "memory"); \
                 __builtin_amdgcn_sched_barrier(0); }

// Roles: 0 = L0 recurrence, 1 = L1 x-GEMV (double-buffered), 2 = L1 rec + fc.
// 192 blocks x 1024 threads (16 waves). waves_per_eu(4,4) => <=128 VGPR =>
// 16 waves/CU => 1 block/CU; 192 blocks < 256 CUs => co-residency by capacity.
// Per-thread pressure ~100 VGPR (within the allocator's demonstrated grants).
__global__
__attribute__((amdgpu_flat_work_group_size(1024, 1024)))
__attribute__((amdgpu_waves_per_eu(4, 4)))
void gru_pipe(
    const float* __restrict__ data,   const float* __restrict__ hidden,
    const float* __restrict__ w_ih0,  const float* __restrict__ w_hh0,
    const float* __restrict__ b_ih0,  const float* __restrict__ b_hh0,
    const float* __restrict__ w_ih1,  const float* __restrict__ w_hh1,
    const float* __restrict__ b_ih1,  const float* __restrict__ b_hh1,
    const float* __restrict__ fc_w,   const float* __restrict__ fc_b,
    float* __restrict__ out, float* __restrict__ wsf)
{
    const int bid  = blockIdx.x;
    const int role = bid >> 6;      // 0..2
    const int b    = bid & 63;
    const int tid  = threadIdx.x;
    const int u    = tid >> 3;      // hidden unit 0..127
    const int c    = tid & 7;       // col-chunk lane in the 8-lane group

    float* y0r = wsf;                               // [BB][RR][128]
    float* xgr = wsf + BB*RR*128;                   // [BB][RR][384]
    unsigned* fl   = (unsigned*)(wsf + BB*RR*128 + BB*RR*384);
    unsigned* yflag = fl + 0*BB*RR + b*RR;
    unsigned* ycons = fl + 1*BB*RR + b*RR;
    unsigned* xflag = fl + 2*BB*RR + b*RR;
    unsigned* xcons = fl + 3*BB*RR + b*RR;

    __shared__ __align__(16) float hs[128];
    __shared__ float xs[TT];                        // role-0 input stage (16 KB)

    bool dead = false;

    if (role == 0) {
        // ----------------------------- L0 recurrence -----------------------------
        X4(DECLW)
        { const float* rpA = w_hh0 + u*128 + 4*c;
          const float* rpB = rpA + 16384; const float* rpC = rpA + 32768;
          X4(LDW) }
        X4(PINW)
        const float br  = b_ih0[u]       + b_hh0[u];
        const float bz  = b_ih0[u + 128] + b_hh0[u + 128];
        const float bin = b_ih0[u + 256];
        const float bhn = b_hh0[u + 256];
        const float wir = w_ih0[u], wiz = w_ih0[u + 128], win = w_ih0[u + 256];

        float hold = hidden[b*128 + u];
        if (tid < 128) hs[tid] = hidden[b*128 + tid];
        { const float* xp = data + (size_t)b*TT;
          for (int i = tid; i < TT; i += 1024) xs[i] = xp[i]; }
        __syncthreads();

        const float4* hb4 = (const float4*)hs;
        float* yr = y0r + (size_t)b*RR*128;
        unsigned g = 0;

        for (int t = 0; t < TT; ++t) {
            const int s = t & (RR - 1);
            if (tid == 0 && t >= RR) {              // barrier below gates the others
                WAIT_EQ(&ycons[s], t - RR + 1, g, dead)
            }
            const float xv = xs[t];
            float a0 = 0.f, a1 = 0.f, a2 = 0.f;
            X4(GEMV_LDS)
            RED3()
            const float r = sigm(fmaf(xv, wir, A0 + br));
            const float z = sigm(fmaf(xv, wiz, A1 + bz));
            const float n = tanhfast(fmaf(r, A2 + bhn, fmaf(xv, win, bin)));
            const float hnew = fmaf(z, hold - n, n);
            __syncthreads();                         // readers done + poll joined
            if (c == 0) { hs[u] = hnew; SYS_STF(&yr[s*128 + u], hnew); }
            __syncthreads();                         // drains vmcnt: y0 visible
            if (tid == 0) SYS_STU(&yflag[s], (unsigned)(t + 1));
            if (t + 1 >= RR) g = SYS_LDU(&ycons[(t + 1) & (RR - 1)]);  // prefetch
            hold = hnew;
        }
        if (tid < 128) out[OUT_HID + b*128 + tid] = hs[tid];

    } else if (role == 1) {
        // --------- L1 x-side GEMV, double-buffered y (issue-early/wait-late) ---------
        X4(DECLW)
        { const float* rpA = w_ih1 + u*128 + 4*c;
          const float* rpB = rpA + 16384; const float* rpC = rpA + 32768;
          X4(LDW) }
        X4(PINW)
        float4 yA0, yA1, yA2, yA3, yB0, yB1, yB2, yB3;
        float* xg = xgr + (size_t)b*RR*384;
        const float* yrd = y0r + (size_t)b*RR*128;

        unsigned fy = SYS_LDU(&yflag[0]);
        WAIT_EQ(&yflag[0], 1, fy, dead)
        { const float* p = yrd + 4*c; LOADY(yA0, yA1, yA2, yA3, p) }
        fy = SYS_LDU(&yflag[1]);
        unsigned fx = 0;

        for (int t = 0; t < TT; t += 2) {
            { // ---- step t: compute bank A, load y[t+1] -> bank B ----
                const int sn = (t + 1) & (RR - 1);
                WAIT_EQ(&yflag[sn], t + 2, fy, dead)
                WAITV                                // bank A landed
                { const float* p = yrd + sn*128 + 4*c; LOADY(yB0, yB1, yB2, yB3, p) }
                fy = SYS_LDU(&yflag[(t + 2) & (RR - 1)]);
                const int s = t & (RR - 1);
                if (t >= RR) { WAIT_EQ(&xcons[s], t - RR + 1, fx, dead) }
                fx = SYS_LDU(&xcons[(t + 1) & (RR - 1)]);
                float a0 = 0.f, a1 = 0.f, a2 = 0.f;
                X4(GEMV_YA)
                RED3()
                if (c == 0) {
                    SYS_STF(&xg[s*384 + u],       A0);
                    SYS_STF(&xg[s*384 + 128 + u], A1);
                    SYS_STF(&xg[s*384 + 256 + u], A2);
                }
                __syncthreads();                     // drains vmcnt: xg visible
                if (tid == 0) {
                    SYS_STU(&xflag[s], (unsigned)(t + 1));
                    SYS_STU(&ycons[s], (unsigned)(t + 1));
                }
            }
            { // ---- step t+1: compute bank B, load y[t+2] -> bank A ----
                const int tt = t + 1;
                if (tt + 1 < TT) {
                    const int sn = (tt + 1) & (RR - 1);
                    WAIT_EQ(&yflag[sn], tt + 2, fy, dead)
                    WAITV                            // bank B landed
                    { const float* p = yrd + sn*128 + 4*c; LOADY(yA0, yA1, yA2, yA3, p) }
                    fy = SYS_LDU(&yflag[(tt + 2) & (RR - 1)]);
                } else {
                    WAITV
                }
                const int s = tt & (RR - 1);
                if (tt >= RR) { WAIT_EQ(&xcons[s], tt - RR + 1, fx, dead) }
                fx = SYS_LDU(&xcons[(tt + 1) & (RR - 1)]);
                float a0 = 0.f, a1 = 0.f, a2 = 0.f;
                X4(GEMV_YB)
                RED3()
                if (c == 0) {
                    SYS_STF(&xg[s*384 + u],       A0);
                    SYS_STF(&xg[s*384 + 128 + u], A1);
                    SYS_STF(&xg[s*384 + 256 + u], A2);
                }
                __syncthreads();
                if (tid == 0) {
                    SYS_STU(&xflag[s], (unsigned)(tt + 1));
                    SYS_STU(&ycons[s], (unsigned)(tt + 1));
                }
            }
        }

    } else {
        // ------------------------ L1 recurrence + fc head ------------------------
        X4(DECLW)
        { const float* rpA = w_hh1 + u*128 + 4*c;
          const float* rpB = rpA + 16384; const float* rpC = rpA + 32768;
          X4(LDW) }
        X4(PINW)
        const float br  = b_ih1[u]       + b_hh1[u];
        const float bz  = b_ih1[u + 128] + b_hh1[u + 128];
        const float bin = b_ih1[u + 256];
        const float bhn = b_hh1[u + 256];
        float fw0 = 0.f, fw1 = 0.f, fb = 0.f;
        if (tid < 64) { fw0 = fc_w[tid]; fw1 = fc_w[tid + 64]; fb = fc_b[0]; }

        float hold = hidden[8192 + b*128 + u];
        if (tid < 128) hs[tid] = hidden[8192 + b*128 + tid];
        __syncthreads();

        const float4* hb4 = (const float4*)hs;
        const float* xgd = xgr + (size_t)b*RR*384;
        float* outp = out + (size_t)b*TT;
        unsigned f = SYS_LDU(&xflag[0]);

        for (int t = 0; t < TT; ++t) {
            const int s = t & (RR - 1);
            WAIT_EQ(&xflag[s], t + 1, f, dead)
            const float* xgp = xgd + s*384 + u;
            float xr, xz, xn;
            asm volatile(                            // issue-early, wait-late
                "global_load_dword %0, %3, off sc0 sc1\n\t"
                "global_load_dword %1, %3, off offset:512 sc0 sc1\n\t"
                "global_load_dword %2, %3, off offset:1024 sc0 sc1"
                : "=&v"(xr), "=&v"(xz), "=&v"(xn) : "v"(xgp) : "memory");
            if (t + 1 < TT) f = SYS_LDU(&xflag[(t + 1) & (RR - 1)]);   // prefetch poll
            float fcv = 0.f;
            if (tid < 64 && t >= 1)
                fcv = fmaxf(hs[tid], 0.f)*fw0 + fmaxf(hs[tid + 64], 0.f)*fw1;
            float a0 = 0.f, a1 = 0.f, a2 = 0.f;
            X4(GEMV_LDS)                             // xg latency hides under this
            RED3()
            asm volatile("s_waitcnt vmcnt(0)" : "+v"(xr), "+v"(xz), "+v"(xn));
            __builtin_amdgcn_sched_barrier(0);
            const float r = sigm(xr + A0 + br);
            const float z = sigm(xz + A1 + bz);
            const float n = tanhfast(fmaf(r, A2 + bhn, xn + bin));
            const float hnew = fmaf(z, hold - n, n);
            if (tid < 64 && t >= 1) {
#pragma unroll
                for (int off = 1; off < 64; off <<= 1) fcv += __shfl_xor(fcv, off);
                if (tid == 0) outp[t - 1] = fcv + fb;
            }
            __syncthreads();
            if (c == 0) hs[u] = hnew;
            __syncthreads();
            if (tid == 0) SYS_STU(&xcons[s], (unsigned)(t + 1));
            hold = hnew;
        }
        float fcv = 0.f;
        if (tid < 64) {
            fcv = fmaxf(hs[tid], 0.f)*fw0 + fmaxf(hs[tid + 64], 0.f)*fw1;
#pragma unroll
            for (int off = 1; off < 64; off <<= 1) fcv += __shfl_xor(fcv, off);
            if (tid == 0) outp[TT - 1] = fcv + fb;
        }
        if (tid < 128) out[OUT_HID + 8192 + b*128 + tid] = hs[tid];
    }
}

extern "C" void kernel_launch(void* const* d_in, const int* in_sizes, int n_in,
                              void* d_out, int out_size, void* d_ws, size_t ws_size,
                              hipStream_t stream) {
    (void)in_sizes; (void)n_in; (void)out_size; (void)ws_size;
    gru_pipe<<<192, 1024, 0, stream>>>(
        (const float*)d_in[0],  (const float*)d_in[1],
        (const float*)d_in[2],  (const float*)d_in[3],
        (const float*)d_in[4],  (const float*)d_in[5],
        (const float*)d_in[6],  (const float*)d_in[7],
        (const float*)d_in[8],  (const float*)d_in[9],
        (const float*)d_in[10], (const float*)d_in[11],
        (float*)d_out, (float*)d_ws);
}